// Round 15
// baseline (215.847 us; speedup 1.0000x reference)
//
#include <hip/hip_runtime.h>

#define PP    32      // nodes per graph
#define FF    16      // input features
#define HH    4       // heads
#define CC    32      // head dim
#define DD    128     // hidden (H*C)
#define EDIM  5
#define EPG   992     // edges per graph = P*(P-1)
#define NB    512     // graphs

typedef float v2f __attribute__((ext_vector_type(2)));
typedef int   v2i __attribute__((ext_vector_type(2)));

// packed 2xfp32 fma (v_pk_fma_f32 on CDNA); per-component order == scalar
__device__ __forceinline__ v2f fma2(v2f a, v2f b, v2f c) {
#if __has_builtin(__builtin_elementwise_fma)
    return __builtin_elementwise_fma(a, b, c);
#else
    v2f r; r.x = __builtin_fmaf(a.x, b.x, c.x); r.y = __builtin_fmaf(a.y, b.y, c.y); return r;
#endif
}
__device__ __forceinline__ v2f abs2(v2f v) {
    v2i t = __builtin_bit_cast(v2i, v);
    t.x &= 0x7fffffff; t.y &= 0x7fffffff;
    return __builtin_bit_cast(v2f, t);
}

// ---- DPP helpers (HW-validated R4) ------------------------------------------
template <int CTRL>
__device__ __forceinline__ float dpp_add(float v) {
    int t = __builtin_amdgcn_update_dpp(0, __builtin_bit_cast(int, v), CTRL, 0xF, 0xF, true);
    return v + __builtin_bit_cast(float, t);
}
template <int CTRL>
__device__ __forceinline__ float dpp_mov(float v) {
    int t = __builtin_amdgcn_update_dpp(0, __builtin_bit_cast(int, v), CTRL, 0xF, 0xF, true);
    return __builtin_bit_cast(float, t);
}
// full 64-lane sum -> result valid in lane 63
__device__ __forceinline__ float red64(float v) {
    v = dpp_add<0x111>(v);   // row_shr:1
    v = dpp_add<0x112>(v);   // row_shr:2
    v = dpp_add<0x114>(v);   // row_shr:4
    v = dpp_add<0x118>(v);   // row_shr:8
    v = dpp_add<0x142>(v);   // row_bcast:15
    v = dpp_add<0x143>(v);   // row_bcast:31
    return v;
}
// quad butterfly sum -> all 4 lanes hold the sum
__device__ __forceinline__ float redquad(float v) {
    v = dpp_add<0xB1>(v);    // quad_perm [1,0,3,2]  (xor 1)
    v = dpp_add<0x4E>(v);    // quad_perm [2,3,0,1]  (xor 2)
    return v;
}
// quad butterfly max -> all 4 lanes hold the max
__device__ __forceinline__ float maxquad(float v) {
    v = fmaxf(v, dpp_mov<0xB1>(v));
    v = fmaxf(v, dpp_mov<0x4E>(v));
    return v;
}

// ---- GATv2 layer (R8 structure + R15 pk-packed score/agg) -------------------
// Score phase lane map: s = tid>>4, h = (tid>>2)&3, c4 = tid&3, ch0=(tid&15)*8.
// Channel pairs (2cp, 2cp+1) ride one VGPR pair: .x accumulates even channels
// in the same order as the old acc0, .y the odd channels (old acc1) -> packed
// v_pk_fma_f32 with BIT-IDENTICAL results (final sum accp.x+accp.y == acc0+acc1).
// Edge attrs STAGED INTO LDS (sE == sOut, dead during score phase) in two
// d-halves (16 KB).  Diagonal d==s staged from a clamped in-bounds edge and
// discarded by softmax.  sS layout: sS[s*128 + d*4 + h].
__device__ __forceinline__ void attention(const float* __restrict__ eattr,
                                          const float* __restrict__ We, const float* __restrict__ att,
                                          const float* __restrict__ bias,
                                          const float* __restrict__ sMsg, const float* __restrict__ sDst,
                                          float* __restrict__ sS, float* __restrict__ sOut,
                                          int tid, long eBase, bool relu)
{
    float* __restrict__ sE = sOut;                    // staging alias (dead until aggregation)
    {
        const int s  = tid >> 4;
        const int ch0 = (tid & 15) * 8;               // h*32 + c4*8
        // packed preload: wp[cp*5+k] = {We[2cp][k], We[2cp+1][k]}, atp, xlp
        v2f wp[20], atp[4], xlp[4];
#pragma unroll
        for (int cp = 0; cp < 4; ++cp) {
            const float* base = We + (ch0 + 2 * cp) * EDIM;   // 10 floats, 8B-aligned
            const v2f g0 = *(const v2f*)(base);               // ev k0,k1
            const v2f g1 = *(const v2f*)(base + 2);           // ev k2,k3
            const v2f g2 = *(const v2f*)(base + 4);           // ev k4, od k0
            const v2f g3 = *(const v2f*)(base + 6);           // od k1,k2
            const v2f g4 = *(const v2f*)(base + 8);           // od k3,k4
            wp[cp * 5 + 0] = (v2f){g0.x, g2.y};
            wp[cp * 5 + 1] = (v2f){g0.y, g3.x};
            wp[cp * 5 + 2] = (v2f){g1.x, g3.y};
            wp[cp * 5 + 3] = (v2f){g1.y, g4.x};
            wp[cp * 5 + 4] = (v2f){g2.x, g4.y};
            atp[cp] = *(const v2f*)(att + ch0 + 2 * cp);
            xlp[cp] = *(const v2f*)(sMsg + s * DD + ch0 + 2 * cp);
        }
        const v2f c06 = (v2f){0.6f, 0.6f};
        const v2f c04 = (v2f){0.4f, 0.4f};

        for (int halfd = 0; halfd < 2; ++halfd) {
            const int d0 = halfd * 16;
            // ---- stage edges (s, d0 + dl): one edge per thread (32s x 16d)
            {
                const int dl = tid & 15;
                const int d = d0 + dl;
                int jj = d - (d > s);
                if (jj > 30) jj = 30;                 // d==s==31 clamp (discarded)
                const float* ea = eattr + (eBase + s * 31 + jj) * EDIM;
                const float e0 = ea[0], e1 = ea[1], e2 = ea[2], e3 = ea[3], e4 = ea[4];
                float* p = sE + (((s << 4) | dl) << 3);
                *(float4*)p = make_float4(e0, e1, e2, e3);
                p[4] = e4;
            }
            __syncthreads();
            // ---- score loop over this d-half: LDS reads + packed math
#pragma unroll 2
            for (int dl = 0; dl < 16; ++dl) {
                const int d = d0 + dl;
                const float* ep = sE + (((s << 4) | dl) << 3);
                const float4 ef = *(const float4*)ep;
                const float e4v = ep[4];
                const v2f e0v = (v2f){ef.x, ef.x};
                const v2f e1v = (v2f){ef.y, ef.y};
                const v2f e2v = (v2f){ef.z, ef.z};
                const v2f e3v = (v2f){ef.w, ef.w};
                const v2f e4p = (v2f){e4v, e4v};
                float xr[8];
                *(float4*)(xr)     = *(const float4*)(sDst + d * DD + ch0);
                *(float4*)(xr + 4) = *(const float4*)(sDst + d * DD + ch0 + 4);
                v2f accp = (v2f){0.f, 0.f};
#pragma unroll
                for (int cp = 0; cp < 4; ++cp) {
                    v2f v = xlp[cp] + *(const v2f*)(xr + 2 * cp);
                    const v2f* w = wp + cp * 5;
                    v = fma2(w[0], e0v, v); v = fma2(w[1], e1v, v); v = fma2(w[2], e2v, v);
                    v = fma2(w[3], e3v, v); v = fma2(w[4], e4p, v);
                    v = fma2(c04, abs2(v), v * c06);  // leaky_relu(., 0.2)
                    accp = fma2(v, atp[cp], accp);
                }
                const float r = redquad(accp.x + accp.y); // == redquad(acc0+acc1)
                if ((tid & 3) == 0)
                    sS[s * DD + d * HH + ((tid >> 2) & 3)] = r;
            }
            __syncthreads();                              // sE half consumed
        }
    }
    // ---- segment softmax over s != d per column (d*4+h): all 512 threads,
    // quad per column, r = tid&3 owns 8 rows, DPP quad reduce.
    {
        const int col = tid >> 2;
        const int r   = tid & 3;
        const int dd  = col >> 2;                     // destination node of this column
        float v[8];
        float mx = -3.4e38f;
#pragma unroll
        for (int i = 0; i < 8; ++i) {
            const int s = r * 8 + i;
            v[i] = sS[s * DD + col];
            mx = (s == dd) ? mx : fmaxf(mx, v[i]);
        }
        mx = maxquad(mx);
        float sum = 0.f;
#pragma unroll
        for (int i = 0; i < 8; ++i) {
            const int s = r * 8 + i;
            float ex = __expf(v[i] - mx);
            ex = (s == dd) ? 0.f : ex;                // diagonal forced to 0
            v[i] = ex; sum += ex;
        }
        sum = redquad(sum);
        const float inv = 1.f / (sum + 1e-16f);
#pragma unroll
        for (int i = 0; i < 8; ++i)
            sS[(r * 8 + i) * DD + col] = v[i] * inv;
    }
    __syncthreads();
    // ---- aggregation (pk-packed): acc chains (x,y) and (z,w) ride pairs;
    // per-component accumulation order over s identical to scalar version.
    {
        const int d = tid >> 4, sub = tid & 15;
#pragma unroll
        for (int half = 0; half < 2; ++half) {
            const int ch4 = half * 16 + sub;
            const int idx = d * HH + (ch4 >> 3);
            const float* bp = bias + ch4 * 4;
            v2f a01 = (v2f){bp[0], bp[1]};
            v2f a23 = (v2f){bp[2], bp[3]};
#pragma unroll
            for (int s = 0; s < PP; ++s) {
                const float a = sS[s * DD + idx];     // alpha(d==s) == 0
                const v2f av = (v2f){a, a};
                const float4 xv = *(const float4*)(sMsg + s * DD + ch4 * 4);
                a01 = fma2(av, (v2f){xv.x, xv.y}, a01);
                a23 = fma2(av, (v2f){xv.z, xv.w}, a23);
            }
            float4 acc = make_float4(a01.x, a01.y, a23.x, a23.y);
            if (relu) {
                acc.x = fmaxf(acc.x, 0.f); acc.y = fmaxf(acc.y, 0.f);
                acc.z = fmaxf(acc.z, 0.f); acc.w = fmaxf(acc.w, 0.f);
            }
            *(float4*)(sOut + d * DD + ch4 * 4) = acc;
        }
    }
}

extern "C" __global__ void __launch_bounds__(512)
__attribute__((amdgpu_waves_per_eu(4, 4)))
planetwars_gnn_kernel(const float* __restrict__ x, const float* __restrict__ eattr,
                      const float* __restrict__ W1l, const float* __restrict__ b1l,
                      const float* __restrict__ W1r, const float* __restrict__ b1r,
                      const float* __restrict__ W1e, const float* __restrict__ att1, const float* __restrict__ bias1,
                      const float* __restrict__ W2l, const float* __restrict__ b2l,
                      const float* __restrict__ W2r, const float* __restrict__ b2r,
                      const float* __restrict__ W2e, const float* __restrict__ att2, const float* __restrict__ bias2,
                      const float* __restrict__ Wc1, const float* __restrict__ bc1,
                      const float* __restrict__ Wc2, const float* __restrict__ bc2,
                      const float* __restrict__ Ws1, const float* __restrict__ bs1,
                      const float* __restrict__ Ws2, const float* __restrict__ bs2,
                      const float* __restrict__ Wn1, const float* __restrict__ bn1,
                      const float* __restrict__ Wn2, const float* __restrict__ bn2,
                      float* __restrict__ out)
{
    __shared__ __align__(16) float sA[PP * DD];   // xl1 -> xl2
    __shared__ __align__(16) float sB[PP * DD];   // xr1 -> xr2
    __shared__ __align__(16) float sH[PP * DD];   // edge staging | h1 -> h2
    __shared__ __align__(16) float sU[PP * DD];   // x | scores/alpha | g

    const int tid = threadIdx.x;
    const int g = blockIdx.x;
    const long eBase = (long)g * EPG;

    // ---- load x tile (32x16), one element per thread
    sU[tid] = x[g * PP * FF + tid];
    __syncthreads();

    // ---- layer-1 node transforms (K = 16): xl1 -> sA, xr1 -> sB
    {
        const int j = tid & 127, d0 = (tid >> 7) * 8;
        float wl[16], wr[16];
#pragma unroll
        for (int q = 0; q < 4; ++q) {
            *(float4*)(wl + q * 4) = *(const float4*)(W1l + j * FF + q * 4);
            *(float4*)(wr + q * 4) = *(const float4*)(W1r + j * FF + q * 4);
        }
        const float bl = b1l[j], br = b1r[j];
#pragma unroll
        for (int i = 0; i < 8; ++i) {
            const float* xr = sU + (d0 + i) * FF;
            float al = bl, ar = br;
#pragma unroll
            for (int k = 0; k < FF; ++k) {
                const float xv = xr[k];
                al = fmaf(wl[k], xv, al);
                ar = fmaf(wr[k], xv, ar);
            }
            sA[(d0 + i) * DD + j] = al;
            sB[(d0 + i) * DD + j] = ar;
        }
    }
    __syncthreads();

    attention(eattr, W1e, att1, bias1, sA, sB, sU, sH, tid, eBase, false);
    __syncthreads();

    // ---- MeanSubtractionNorm per graph, then ReLU (512 threads, quad/column)
    {
        const int col = tid >> 2, r = tid & 3;
        float v[8];
        float ssum = 0.f;
#pragma unroll
        for (int i = 0; i < 8; ++i) {
            v[i] = sH[(r * 8 + i) * DD + col];
            ssum += v[i];
        }
        ssum = redquad(ssum);
        const float mn = ssum * (1.0f / 32.0f);
#pragma unroll
        for (int i = 0; i < 8; ++i)
            sH[(r * 8 + i) * DD + col] = fmaxf(v[i] - mn, 0.f);
    }
    __syncthreads();

    // ---- fused layer-2 node transforms (K = 128), register-weight scheme
    // (R14-proven: single float4 weight stream, no spill, bit-identical).
    {
        const int j    = tid & 127;
        const int m    = (tid >> 7) & 1;
        const int half = tid >> 8;                    // wave-uniform
        const float* Wrow = (m ? W2r : W2l) + j * DD;
        const float  bini = m ? b2r[j] : b2l[j];
        float acc[16];
#pragma unroll
        for (int i = 0; i < 16; ++i) acc[i] = bini;
        for (int kc = 0; kc < 32; ++kc) {
            const float4 w4 = *(const float4*)(Wrow + kc * 4);
#pragma unroll
            for (int i = 0; i < 16; ++i) {
                const float4 hv = *(const float4*)(sH + (half * 16 + i) * DD + kc * 4);
                acc[i] = fmaf(w4.x, hv.x, acc[i]);
                acc[i] = fmaf(w4.y, hv.y, acc[i]);
                acc[i] = fmaf(w4.z, hv.z, acc[i]);
                acc[i] = fmaf(w4.w, hv.w, acc[i]);
            }
        }
        float* dst = m ? sB : sA;
#pragma unroll
        for (int i = 0; i < 16; ++i)
            dst[(half * 16 + i) * DD + j] = acc[i];
    }
    __syncthreads();

    attention(eattr, W2e, att2, bias2, sA, sB, sU, sH, tid, eBase, true);
    __syncthreads();

    // ---- global mean pool -> sU[0..127] (512 threads, quad per column)
    {
        const int col = tid >> 2, r = tid & 3;
        float ssum = 0.f;
#pragma unroll
        for (int i = 0; i < 8; ++i) ssum += sH[(r * 8 + i) * DD + col];
        ssum = redquad(ssum);
        if (r == 0) sU[col] = ssum * (1.0f / 32.0f);
    }
    __syncthreads();

    // ---- source-actor: fused Ws1-GEMM + Ws2 dot -> logits written directly.
    {
        const int jj = tid & 63, d0 = (tid >> 6) * 4;
        const float b0 = bs1[jj], b1 = bs1[jj + 64];
        float acc0[4], acc1[4];
#pragma unroll
        for (int i = 0; i < 4; ++i) { acc0[i] = b0; acc1[i] = b1; }
        const float* W0 = Ws1 + jj * DD;
        const float* W1 = Ws1 + (jj + 64) * DD;
        for (int k8 = 0; k8 < 16; ++k8) {
            const float4 w00 = *(const float4*)(W0 + k8 * 8), w01 = *(const float4*)(W0 + k8 * 8 + 4);
            const float4 w10 = *(const float4*)(W1 + k8 * 8), w11 = *(const float4*)(W1 + k8 * 8 + 4);
#pragma unroll
            for (int i = 0; i < 4; ++i) {
                const float4 a0 = *(const float4*)(sH + (d0 + i) * DD + k8 * 8);
                const float4 a1 = *(const float4*)(sH + (d0 + i) * DD + k8 * 8 + 4);
                acc0[i] = fmaf(w00.x, a0.x, acc0[i]); acc0[i] = fmaf(w00.y, a0.y, acc0[i]);
                acc0[i] = fmaf(w00.z, a0.z, acc0[i]); acc0[i] = fmaf(w00.w, a0.w, acc0[i]);
                acc0[i] = fmaf(w01.x, a1.x, acc0[i]); acc0[i] = fmaf(w01.y, a1.y, acc0[i]);
                acc0[i] = fmaf(w01.z, a1.z, acc0[i]); acc0[i] = fmaf(w01.w, a1.w, acc0[i]);
                acc1[i] = fmaf(w10.x, a0.x, acc1[i]); acc1[i] = fmaf(w10.y, a0.y, acc1[i]);
                acc1[i] = fmaf(w10.z, a0.z, acc1[i]); acc1[i] = fmaf(w10.w, a0.w, acc1[i]);
                acc1[i] = fmaf(w11.x, a1.x, acc1[i]); acc1[i] = fmaf(w11.y, a1.y, acc1[i]);
                acc1[i] = fmaf(w11.z, a1.z, acc1[i]); acc1[i] = fmaf(w11.w, a1.w, acc1[i]);
            }
        }
        const float ws2a = Ws2[jj], ws2b = Ws2[jj + 64];
        const float bias2s = bs2[0];
#pragma unroll
        for (int i = 0; i < 4; ++i) {
            const float t = fmaf(fmaxf(acc0[i], 0.f), ws2a, fmaxf(acc1[i], 0.f) * ws2b);
            const float r = red64(t);                 // lane 63 holds node logit
            if ((tid & 63) == 63) out[g * 34 + 2 + d0 + i] = r + bias2s;
        }
    }

    // ---- value / noop: wave 0 = critic, wave 1 = noop (fused hidden + dot)
    if (tid < 128) {
        const int w = tid >> 6, j = tid & 63;
        const float* Wa = (w ? Wn1 : Wc1);
        const float* ba = (w ? bn1 : bc1);
        const float* Wb = (w ? Wn2 : Wc2);
        const float  bb = (w ? bn2 : bc2)[0];
        float h0 = ba[j], h1 = ba[j + 64];
        const float* R0 = Wa + j * DD;
        const float* R1 = Wa + (j + 64) * DD;
#pragma unroll
        for (int k8 = 0; k8 < 16; ++k8) {
            const float4 g0 = *(const float4*)(sU + k8 * 8);
            const float4 g1 = *(const float4*)(sU + k8 * 8 + 4);
            const float4 p00 = *(const float4*)(R0 + k8 * 8), p01 = *(const float4*)(R0 + k8 * 8 + 4);
            const float4 p10 = *(const float4*)(R1 + k8 * 8), p11 = *(const float4*)(R1 + k8 * 8 + 4);
            h0 = fmaf(p00.x, g0.x, h0); h0 = fmaf(p00.y, g0.y, h0);
            h0 = fmaf(p00.z, g0.z, h0); h0 = fmaf(p00.w, g0.w, h0);
            h0 = fmaf(p01.x, g1.x, h0); h0 = fmaf(p01.y, g1.y, h0);
            h0 = fmaf(p01.z, g1.z, h0); h0 = fmaf(p01.w, g1.w, h0);
            h1 = fmaf(p10.x, g0.x, h1); h1 = fmaf(p10.y, g0.y, h1);
            h1 = fmaf(p10.z, g0.z, h1); h1 = fmaf(p10.w, g0.w, h1);
            h1 = fmaf(p11.x, g1.x, h1); h1 = fmaf(p11.y, g1.y, h1);
            h1 = fmaf(p11.z, g1.z, h1); h1 = fmaf(p11.w, g1.w, h1);
        }
        const float t = fmaf(fmaxf(h0, 0.f), Wb[j], fmaxf(h1, 0.f) * Wb[j + 64]);
        const float r = red64(t);
        if (j == 63) out[g * 34 + w] = r + bb;
    }
}

extern "C" void kernel_launch(void* const* d_in, const int* in_sizes, int n_in,
                              void* d_out, int out_size, void* d_ws, size_t ws_size,
                              hipStream_t stream)
{
    (void)in_sizes; (void)n_in; (void)d_ws; (void)ws_size; (void)out_size;
    // d_in[1] (edge_index) unused: edge structure is analytic (validated R3).
    planetwars_gnn_kernel<<<dim3(NB), dim3(512), 0, stream>>>(
        (const float*)d_in[0], (const float*)d_in[2],
        (const float*)d_in[3], (const float*)d_in[4], (const float*)d_in[5], (const float*)d_in[6],
        (const float*)d_in[7], (const float*)d_in[8], (const float*)d_in[9],
        (const float*)d_in[10], (const float*)d_in[11], (const float*)d_in[12], (const float*)d_in[13],
        (const float*)d_in[14], (const float*)d_in[15], (const float*)d_in[16],
        (const float*)d_in[17], (const float*)d_in[18], (const float*)d_in[19], (const float*)d_in[20],
        (const float*)d_in[21], (const float*)d_in[22], (const float*)d_in[23], (const float*)d_in[24],
        (const float*)d_in[25], (const float*)d_in[26], (const float*)d_in[27], (const float*)d_in[28],
        (float*)d_out);
}

// Round 16
// 213.665 us; speedup vs baseline: 1.0102x; 1.0102x over previous
//
#include <hip/hip_runtime.h>

#define PP    32      // nodes per graph
#define FF    16      // input features
#define HH    4       // heads
#define CC    32      // head dim
#define DD    128     // hidden (H*C)
#define EDIM  5
#define EPG   992     // edges per graph = P*(P-1)
#define NB    512     // graphs

typedef float v2f __attribute__((ext_vector_type(2)));
typedef int   v2i __attribute__((ext_vector_type(2)));

// packed 2xfp32 fma (v_pk_fma_f32 on CDNA); per-component order == scalar
__device__ __forceinline__ v2f fma2(v2f a, v2f b, v2f c) {
#if __has_builtin(__builtin_elementwise_fma)
    return __builtin_elementwise_fma(a, b, c);
#else
    v2f r; r.x = __builtin_fmaf(a.x, b.x, c.x); r.y = __builtin_fmaf(a.y, b.y, c.y); return r;
#endif
}
__device__ __forceinline__ v2f abs2(v2f v) {
    v2i t = __builtin_bit_cast(v2i, v);
    t.x &= 0x7fffffff; t.y &= 0x7fffffff;
    return __builtin_bit_cast(v2f, t);
}

// ---- DPP helpers (HW-validated R4) ------------------------------------------
template <int CTRL>
__device__ __forceinline__ float dpp_add(float v) {
    int t = __builtin_amdgcn_update_dpp(0, __builtin_bit_cast(int, v), CTRL, 0xF, 0xF, true);
    return v + __builtin_bit_cast(float, t);
}
template <int CTRL>
__device__ __forceinline__ float dpp_mov(float v) {
    int t = __builtin_amdgcn_update_dpp(0, __builtin_bit_cast(int, v), CTRL, 0xF, 0xF, true);
    return __builtin_bit_cast(float, t);
}
// full 64-lane sum -> result valid in lane 63
__device__ __forceinline__ float red64(float v) {
    v = dpp_add<0x111>(v);   // row_shr:1
    v = dpp_add<0x112>(v);   // row_shr:2
    v = dpp_add<0x114>(v);   // row_shr:4
    v = dpp_add<0x118>(v);   // row_shr:8
    v = dpp_add<0x142>(v);   // row_bcast:15
    v = dpp_add<0x143>(v);   // row_bcast:31
    return v;
}
// quad butterfly sum -> all 4 lanes hold the sum
__device__ __forceinline__ float redquad(float v) {
    v = dpp_add<0xB1>(v);    // quad_perm [1,0,3,2]  (xor 1)
    v = dpp_add<0x4E>(v);    // quad_perm [2,3,0,1]  (xor 2)
    return v;
}
// quad butterfly max -> all 4 lanes hold the max
__device__ __forceinline__ float maxquad(float v) {
    v = fmaxf(v, dpp_mov<0xB1>(v));
    v = fmaxf(v, dpp_mov<0x4E>(v));
    return v;
}

// ---- GATv2 layer (R15 pk-packed + R16 single-stage edge buffer) -------------
// Score phase lane map: s = tid>>4, h = (tid>>2)&3, ch0 = (tid&15)*8.
// Channel pairs (2cp, 2cp+1) ride one VGPR pair (v_pk_fma_f32, bit-identical).
// R16: edges staged ONCE for all 32 d (e0-e3 -> sE float4 = 16 KB exactly,
// e4 -> dedicated sE4 4 KB buffer).  Occupancy is grid-pinned at 2 blocks/CU,
// so the extra 4 KB LDS is free.  One uninterrupted 32-iter score loop:
// 2 fewer barriers per attention + 2x deeper load-pipelining window.
// Diagonal d==s staged from a clamped in-bounds edge, discarded by softmax.
// sS layout: sS[s*128 + d*4 + h].
__device__ __forceinline__ void attention(const float* __restrict__ eattr,
                                          const float* __restrict__ We, const float* __restrict__ att,
                                          const float* __restrict__ bias,
                                          const float* __restrict__ sMsg, const float* __restrict__ sDst,
                                          float* __restrict__ sS, float* __restrict__ sOut,
                                          float* __restrict__ sE4,
                                          int tid, long eBase, bool relu)
{
    float* __restrict__ sE = sOut;                    // staging alias (dead until aggregation)
    {
        const int s  = tid >> 4;
        const int ch0 = (tid & 15) * 8;               // h*32 + c4*8
        // packed preload: wp[cp*5+k] = {We[2cp][k], We[2cp+1][k]}, atp, xlp
        v2f wp[20], atp[4], xlp[4];
#pragma unroll
        for (int cp = 0; cp < 4; ++cp) {
            const float* base = We + (ch0 + 2 * cp) * EDIM;   // 10 floats, 8B-aligned
            const v2f g0 = *(const v2f*)(base);               // ev k0,k1
            const v2f g1 = *(const v2f*)(base + 2);           // ev k2,k3
            const v2f g2 = *(const v2f*)(base + 4);           // ev k4, od k0
            const v2f g3 = *(const v2f*)(base + 6);           // od k1,k2
            const v2f g4 = *(const v2f*)(base + 8);           // od k3,k4
            wp[cp * 5 + 0] = (v2f){g0.x, g2.y};
            wp[cp * 5 + 1] = (v2f){g0.y, g3.x};
            wp[cp * 5 + 2] = (v2f){g1.x, g3.y};
            wp[cp * 5 + 3] = (v2f){g1.y, g4.x};
            wp[cp * 5 + 4] = (v2f){g2.x, g4.y};
            atp[cp] = *(const v2f*)(att + ch0 + 2 * cp);
            xlp[cp] = *(const v2f*)(sMsg + s * DD + ch0 + 2 * cp);
        }
        const v2f c06 = (v2f){0.6f, 0.6f};
        const v2f c04 = (v2f){0.4f, 0.4f};

        // ---- stage ALL edges (s, d): each thread stages 2 edges (d, d+16)
#pragma unroll
        for (int t = 0; t < 2; ++t) {
            const int d = (tid & 15) + t * 16;
            int jj = d - (d > s);
            if (jj > 30) jj = 30;                     // d==s==31 clamp (discarded)
            const float* ea = eattr + (eBase + s * 31 + jj) * EDIM;
            const float e0 = ea[0], e1 = ea[1], e2 = ea[2], e3 = ea[3], e4 = ea[4];
            const int slot = (s << 5) | d;
            *(float4*)(sE + (slot << 2)) = make_float4(e0, e1, e2, e3);
            sE4[slot] = e4;
        }
        __syncthreads();
        // ---- score loop over ALL 32 d: LDS reads + packed math, no barriers
#pragma unroll 2
        for (int d = 0; d < PP; ++d) {
            const int slot = (s << 5) | d;
            const float4 ef = *(const float4*)(sE + (slot << 2));
            const float e4v = sE4[slot];
            const v2f e0v = (v2f){ef.x, ef.x};
            const v2f e1v = (v2f){ef.y, ef.y};
            const v2f e2v = (v2f){ef.z, ef.z};
            const v2f e3v = (v2f){ef.w, ef.w};
            const v2f e4p = (v2f){e4v, e4v};
            float xr[8];
            *(float4*)(xr)     = *(const float4*)(sDst + d * DD + ch0);
            *(float4*)(xr + 4) = *(const float4*)(sDst + d * DD + ch0 + 4);
            v2f accp = (v2f){0.f, 0.f};
#pragma unroll
            for (int cp = 0; cp < 4; ++cp) {
                v2f v = xlp[cp] + *(const v2f*)(xr + 2 * cp);
                const v2f* w = wp + cp * 5;
                v = fma2(w[0], e0v, v); v = fma2(w[1], e1v, v); v = fma2(w[2], e2v, v);
                v = fma2(w[3], e3v, v); v = fma2(w[4], e4p, v);
                v = fma2(c04, abs2(v), v * c06);      // leaky_relu(., 0.2)
                accp = fma2(v, atp[cp], accp);
            }
            const float r = redquad(accp.x + accp.y); // == redquad(acc0+acc1)
            if ((tid & 3) == 0)
                sS[s * DD + d * HH + ((tid >> 2) & 3)] = r;
        }
        __syncthreads();                              // scores complete, sE consumed
    }
    // ---- segment softmax over s != d per column (d*4+h): all 512 threads,
    // quad per column, r = tid&3 owns 8 rows, DPP quad reduce.
    {
        const int col = tid >> 2;
        const int r   = tid & 3;
        const int dd  = col >> 2;                     // destination node of this column
        float v[8];
        float mx = -3.4e38f;
#pragma unroll
        for (int i = 0; i < 8; ++i) {
            const int s = r * 8 + i;
            v[i] = sS[s * DD + col];
            mx = (s == dd) ? mx : fmaxf(mx, v[i]);
        }
        mx = maxquad(mx);
        float sum = 0.f;
#pragma unroll
        for (int i = 0; i < 8; ++i) {
            const int s = r * 8 + i;
            float ex = __expf(v[i] - mx);
            ex = (s == dd) ? 0.f : ex;                // diagonal forced to 0
            v[i] = ex; sum += ex;
        }
        sum = redquad(sum);
        const float inv = 1.f / (sum + 1e-16f);
#pragma unroll
        for (int i = 0; i < 8; ++i)
            sS[(r * 8 + i) * DD + col] = v[i] * inv;
    }
    __syncthreads();
    // ---- aggregation (pk-packed): acc chains (x,y) and (z,w) ride pairs;
    // per-component accumulation order over s identical to scalar version.
    {
        const int d = tid >> 4, sub = tid & 15;
#pragma unroll
        for (int half = 0; half < 2; ++half) {
            const int ch4 = half * 16 + sub;
            const int idx = d * HH + (ch4 >> 3);
            const float* bp = bias + ch4 * 4;
            v2f a01 = (v2f){bp[0], bp[1]};
            v2f a23 = (v2f){bp[2], bp[3]};
#pragma unroll
            for (int s = 0; s < PP; ++s) {
                const float a = sS[s * DD + idx];     // alpha(d==s) == 0
                const v2f av = (v2f){a, a};
                const float4 xv = *(const float4*)(sMsg + s * DD + ch4 * 4);
                a01 = fma2(av, (v2f){xv.x, xv.y}, a01);
                a23 = fma2(av, (v2f){xv.z, xv.w}, a23);
            }
            float4 acc = make_float4(a01.x, a01.y, a23.x, a23.y);
            if (relu) {
                acc.x = fmaxf(acc.x, 0.f); acc.y = fmaxf(acc.y, 0.f);
                acc.z = fmaxf(acc.z, 0.f); acc.w = fmaxf(acc.w, 0.f);
            }
            *(float4*)(sOut + d * DD + ch4 * 4) = acc;
        }
    }
}

extern "C" __global__ void __launch_bounds__(512)
__attribute__((amdgpu_waves_per_eu(4, 4)))
planetwars_gnn_kernel(const float* __restrict__ x, const float* __restrict__ eattr,
                      const float* __restrict__ W1l, const float* __restrict__ b1l,
                      const float* __restrict__ W1r, const float* __restrict__ b1r,
                      const float* __restrict__ W1e, const float* __restrict__ att1, const float* __restrict__ bias1,
                      const float* __restrict__ W2l, const float* __restrict__ b2l,
                      const float* __restrict__ W2r, const float* __restrict__ b2r,
                      const float* __restrict__ W2e, const float* __restrict__ att2, const float* __restrict__ bias2,
                      const float* __restrict__ Wc1, const float* __restrict__ bc1,
                      const float* __restrict__ Wc2, const float* __restrict__ bc2,
                      const float* __restrict__ Ws1, const float* __restrict__ bs1,
                      const float* __restrict__ Ws2, const float* __restrict__ bs2,
                      const float* __restrict__ Wn1, const float* __restrict__ bn1,
                      const float* __restrict__ Wn2, const float* __restrict__ bn2,
                      float* __restrict__ out)
{
    __shared__ __align__(16) float sA[PP * DD];   // xl1 -> xl2
    __shared__ __align__(16) float sB[PP * DD];   // xr1 -> xr2
    __shared__ __align__(16) float sH[PP * DD];   // edge e0-e3 staging | h1 -> h2
    __shared__ __align__(16) float sU[PP * DD];   // x | scores/alpha | g
    __shared__ __align__(16) float sE4[PP * PP];  // edge e4 staging (4 KB; free:
                                                  // occupancy is grid-pinned)

    const int tid = threadIdx.x;
    const int g = blockIdx.x;
    const long eBase = (long)g * EPG;

    // ---- load x tile (32x16), one element per thread
    sU[tid] = x[g * PP * FF + tid];
    __syncthreads();

    // ---- layer-1 node transforms (K = 16): xl1 -> sA, xr1 -> sB
    {
        const int j = tid & 127, d0 = (tid >> 7) * 8;
        float wl[16], wr[16];
#pragma unroll
        for (int q = 0; q < 4; ++q) {
            *(float4*)(wl + q * 4) = *(const float4*)(W1l + j * FF + q * 4);
            *(float4*)(wr + q * 4) = *(const float4*)(W1r + j * FF + q * 4);
        }
        const float bl = b1l[j], br = b1r[j];
#pragma unroll
        for (int i = 0; i < 8; ++i) {
            const float* xr = sU + (d0 + i) * FF;
            float al = bl, ar = br;
#pragma unroll
            for (int k = 0; k < FF; ++k) {
                const float xv = xr[k];
                al = fmaf(wl[k], xv, al);
                ar = fmaf(wr[k], xv, ar);
            }
            sA[(d0 + i) * DD + j] = al;
            sB[(d0 + i) * DD + j] = ar;
        }
    }
    __syncthreads();

    attention(eattr, W1e, att1, bias1, sA, sB, sU, sH, sE4, tid, eBase, false);
    __syncthreads();

    // ---- MeanSubtractionNorm per graph, then ReLU (512 threads, quad/column)
    {
        const int col = tid >> 2, r = tid & 3;
        float v[8];
        float ssum = 0.f;
#pragma unroll
        for (int i = 0; i < 8; ++i) {
            v[i] = sH[(r * 8 + i) * DD + col];
            ssum += v[i];
        }
        ssum = redquad(ssum);
        const float mn = ssum * (1.0f / 32.0f);
#pragma unroll
        for (int i = 0; i < 8; ++i)
            sH[(r * 8 + i) * DD + col] = fmaxf(v[i] - mn, 0.f);
    }
    __syncthreads();

    // ---- fused layer-2 node transforms (K = 128), register-weight scheme
    // (R14-proven: single float4 weight stream, no spill, bit-identical).
    {
        const int j    = tid & 127;
        const int m    = (tid >> 7) & 1;
        const int half = tid >> 8;                    // wave-uniform
        const float* Wrow = (m ? W2r : W2l) + j * DD;
        const float  bini = m ? b2r[j] : b2l[j];
        float acc[16];
#pragma unroll
        for (int i = 0; i < 16; ++i) acc[i] = bini;
        for (int kc = 0; kc < 32; ++kc) {
            const float4 w4 = *(const float4*)(Wrow + kc * 4);
#pragma unroll
            for (int i = 0; i < 16; ++i) {
                const float4 hv = *(const float4*)(sH + (half * 16 + i) * DD + kc * 4);
                acc[i] = fmaf(w4.x, hv.x, acc[i]);
                acc[i] = fmaf(w4.y, hv.y, acc[i]);
                acc[i] = fmaf(w4.z, hv.z, acc[i]);
                acc[i] = fmaf(w4.w, hv.w, acc[i]);
            }
        }
        float* dst = m ? sB : sA;
#pragma unroll
        for (int i = 0; i < 16; ++i)
            dst[(half * 16 + i) * DD + j] = acc[i];
    }
    __syncthreads();

    attention(eattr, W2e, att2, bias2, sA, sB, sU, sH, sE4, tid, eBase, true);
    __syncthreads();

    // ---- global mean pool -> sU[0..127] (512 threads, quad per column)
    {
        const int col = tid >> 2, r = tid & 3;
        float ssum = 0.f;
#pragma unroll
        for (int i = 0; i < 8; ++i) ssum += sH[(r * 8 + i) * DD + col];
        ssum = redquad(ssum);
        if (r == 0) sU[col] = ssum * (1.0f / 32.0f);
    }
    __syncthreads();

    // ---- source-actor: fused Ws1-GEMM + Ws2 dot -> logits written directly.
    {
        const int jj = tid & 63, d0 = (tid >> 6) * 4;
        const float b0 = bs1[jj], b1 = bs1[jj + 64];
        float acc0[4], acc1[4];
#pragma unroll
        for (int i = 0; i < 4; ++i) { acc0[i] = b0; acc1[i] = b1; }
        const float* W0 = Ws1 + jj * DD;
        const float* W1 = Ws1 + (jj + 64) * DD;
        for (int k8 = 0; k8 < 16; ++k8) {
            const float4 w00 = *(const float4*)(W0 + k8 * 8), w01 = *(const float4*)(W0 + k8 * 8 + 4);
            const float4 w10 = *(const float4*)(W1 + k8 * 8), w11 = *(const float4*)(W1 + k8 * 8 + 4);
#pragma unroll
            for (int i = 0; i < 4; ++i) {
                const float4 a0 = *(const float4*)(sH + (d0 + i) * DD + k8 * 8);
                const float4 a1 = *(const float4*)(sH + (d0 + i) * DD + k8 * 8 + 4);
                acc0[i] = fmaf(w00.x, a0.x, acc0[i]); acc0[i] = fmaf(w00.y, a0.y, acc0[i]);
                acc0[i] = fmaf(w00.z, a0.z, acc0[i]); acc0[i] = fmaf(w00.w, a0.w, acc0[i]);
                acc0[i] = fmaf(w01.x, a1.x, acc0[i]); acc0[i] = fmaf(w01.y, a1.y, acc0[i]);
                acc0[i] = fmaf(w01.z, a1.z, acc0[i]); acc0[i] = fmaf(w01.w, a1.w, acc0[i]);
                acc1[i] = fmaf(w10.x, a0.x, acc1[i]); acc1[i] = fmaf(w10.y, a0.y, acc1[i]);
                acc1[i] = fmaf(w10.z, a0.z, acc1[i]); acc1[i] = fmaf(w10.w, a0.w, acc1[i]);
                acc1[i] = fmaf(w11.x, a1.x, acc1[i]); acc1[i] = fmaf(w11.y, a1.y, acc1[i]);
                acc1[i] = fmaf(w11.z, a1.z, acc1[i]); acc1[i] = fmaf(w11.w, a1.w, acc1[i]);
            }
        }
        const float ws2a = Ws2[jj], ws2b = Ws2[jj + 64];
        const float bias2s = bs2[0];
#pragma unroll
        for (int i = 0; i < 4; ++i) {
            const float t = fmaf(fmaxf(acc0[i], 0.f), ws2a, fmaxf(acc1[i], 0.f) * ws2b);
            const float r = red64(t);                 // lane 63 holds node logit
            if ((tid & 63) == 63) out[g * 34 + 2 + d0 + i] = r + bias2s;
        }
    }

    // ---- value / noop: wave 0 = critic, wave 1 = noop (fused hidden + dot)
    if (tid < 128) {
        const int w = tid >> 6, j = tid & 63;
        const float* Wa = (w ? Wn1 : Wc1);
        const float* ba = (w ? bn1 : bc1);
        const float* Wb = (w ? Wn2 : Wc2);
        const float  bb = (w ? bn2 : bc2)[0];
        float h0 = ba[j], h1 = ba[j + 64];
        const float* R0 = Wa + j * DD;
        const float* R1 = Wa + (j + 64) * DD;
#pragma unroll
        for (int k8 = 0; k8 < 16; ++k8) {
            const float4 g0 = *(const float4*)(sU + k8 * 8);
            const float4 g1 = *(const float4*)(sU + k8 * 8 + 4);
            const float4 p00 = *(const float4*)(R0 + k8 * 8), p01 = *(const float4*)(R0 + k8 * 8 + 4);
            const float4 p10 = *(const float4*)(R1 + k8 * 8), p11 = *(const float4*)(R1 + k8 * 8 + 4);
            h0 = fmaf(p00.x, g0.x, h0); h0 = fmaf(p00.y, g0.y, h0);
            h0 = fmaf(p00.z, g0.z, h0); h0 = fmaf(p00.w, g0.w, h0);
            h0 = fmaf(p01.x, g1.x, h0); h0 = fmaf(p01.y, g1.y, h0);
            h0 = fmaf(p01.z, g1.z, h0); h0 = fmaf(p01.w, g1.w, h0);
            h1 = fmaf(p10.x, g0.x, h1); h1 = fmaf(p10.y, g0.y, h1);
            h1 = fmaf(p10.z, g0.z, h1); h1 = fmaf(p10.w, g0.w, h1);
            h1 = fmaf(p11.x, g1.x, h1); h1 = fmaf(p11.y, g1.y, h1);
            h1 = fmaf(p11.z, g1.z, h1); h1 = fmaf(p11.w, g1.w, h1);
        }
        const float t = fmaf(fmaxf(h0, 0.f), Wb[j], fmaxf(h1, 0.f) * Wb[j + 64]);
        const float r = red64(t);
        if (j == 63) out[g * 34 + w] = r + bb;
    }
}

extern "C" void kernel_launch(void* const* d_in, const int* in_sizes, int n_in,
                              void* d_out, int out_size, void* d_ws, size_t ws_size,
                              hipStream_t stream)
{
    (void)in_sizes; (void)n_in; (void)d_ws; (void)ws_size; (void)out_size;
    // d_in[1] (edge_index) unused: edge structure is analytic (validated R3).
    planetwars_gnn_kernel<<<dim3(NB), dim3(512), 0, stream>>>(
        (const float*)d_in[0], (const float*)d_in[2],
        (const float*)d_in[3], (const float*)d_in[4], (const float*)d_in[5], (const float*)d_in[6],
        (const float*)d_in[7], (const float*)d_in[8], (const float*)d_in[9],
        (const float*)d_in[10], (const float*)d_in[11], (const float*)d_in[12], (const float*)d_in[13],
        (const float*)d_in[14], (const float*)d_in[15], (const float*)d_in[16],
        (const float*)d_in[17], (const float*)d_in[18], (const float*)d_in[19], (const float*)d_in[20],
        (const float*)d_in[21], (const float*)d_in[22], (const float*)d_in[23], (const float*)d_in[24],
        (const float*)d_in[25], (const float*)d_in[26], (const float*)d_in[27], (const float*)d_in[28],
        (float*)d_out);
}